// Round 16
// baseline (490.281 us; speedup 1.0000x reference)
//
#include <hip/hip_runtime.h>
#include <hip/hip_bf16.h>
#include <cstdint>

#define HID 256
#define NGRAPH 16
#define NEG_SLOPE 0.01f

typedef __bf16 bf16x8 __attribute__((ext_vector_type(8)));
typedef float f32x4 __attribute__((ext_vector_type(4)));

__device__ __forceinline__ float leaky(float x) { return x >= 0.f ? x : NEG_SLOPE * x; }

__device__ __forceinline__ ushort f2b(float f) {
  uint u = __float_as_uint(f);
  uint r = (u + 0x7fffu + ((u >> 16) & 1u)) >> 16;
  return (ushort)r;
}
__device__ __forceinline__ float b2f(ushort b) { return __uint_as_float((uint)b << 16); }

// ---------------- CSR build ----------------
__global__ __launch_bounds__(256) void k_zero_i32(int* p, int n) {
  int i = blockIdx.x * blockDim.x + threadIdx.x;
  if (i < n) p[i] = 0;
}

__global__ __launch_bounds__(256) void k_hist(const int* __restrict__ key, int* __restrict__ cnt, int ne) {
  int e = blockIdx.x * blockDim.x + threadIdx.x;
  if (e < ne) atomicAdd(&cnt[key[e]], 1);
}

__global__ __launch_bounds__(1024) void k_scan(const int* __restrict__ cnt, int* __restrict__ rowptr,
                                               int* __restrict__ cursor, int n) {
  __shared__ int sd[1024];
  int tid = threadIdx.x;
  int CH = n / 1024 + 1;
  int base = tid * CH;
  int s = 0;
  for (int i = 0; i < CH; ++i) { int idx = base + i; if (idx < n) s += cnt[idx]; }
  sd[tid] = s;
  __syncthreads();
  for (int off = 1; off < 1024; off <<= 1) {
    int v = (tid >= off) ? sd[tid - off] : 0;
    __syncthreads();
    sd[tid] += v;
    __syncthreads();
  }
  int run = (tid == 0) ? 0 : sd[tid - 1];
  for (int i = 0; i < CH; ++i) {
    int idx = base + i;
    if (idx <= n) {
      rowptr[idx] = run;
      if (idx < n) { cursor[idx] = run; run += cnt[idx]; }
    }
  }
}

// batch sorted -> per-graph bounds via binary search
__global__ __launch_bounds__(64) void k_gbounds(const int* __restrict__ batch, int n,
                                                int* __restrict__ gstart, int* __restrict__ gcnt) {
  int t = threadIdx.x;
  if (t <= NGRAPH) {
    int lo = 0, hi = n;
    while (lo < hi) { int mid = (lo + hi) >> 1; if (batch[mid] < t) lo = mid + 1; else hi = mid; }
    gstart[t] = lo;
  }
  __syncthreads();
  if (t < NGRAPH) gcnt[t] = gstart[t + 1] - gstart[t];
}

__global__ __launch_bounds__(256) void k_scatter(const int* __restrict__ src, const int* __restrict__ dst,
                                                 int* __restrict__ cursor, int* __restrict__ col, int ne) {
  int e = blockIdx.x * blockDim.x + threadIdx.x;
  if (e < ne) {
    int d = dst[e];
    int pos = atomicAdd(&cursor[d], 1);
    col[pos] = src[e];
  }
}

// ---------------- conversions ----------------
__global__ __launch_bounds__(256) void k_f2b(const float* __restrict__ src, ushort* __restrict__ dst, int nElem) {
  int i = (blockIdx.x * 256 + threadIdx.x) * 4;
  if (i + 3 < nElem) {
    float4 v = *(const float4*)&src[i];
    ushort4 o;
    o.x = f2b(v.x); o.y = f2b(v.y); o.z = f2b(v.z); o.w = f2b(v.w);
    *(ushort4*)&dst[i] = o;
  } else {
    for (int j = i; j < nElem; ++j) dst[j] = f2b(src[j]);
  }
}

// fused transpose-convert: dst[n][k] = bf16(src[k][n]); src is [K][256]
struct WconvArgs {
  const float* src[9];
  ushort* dst[9];
  int K[9];
};

__global__ __launch_bounds__(256) void k_wconv_all(WconvArgs args) {
  __shared__ float t[32][33];
  const int e = blockIdx.z;
  const int K = args.K[e];
  const int k0 = blockIdx.x * 32;
  if (k0 >= K) return;
  const float* src = args.src[e];
  ushort* dst = args.dst[e];
  const int n0 = blockIdx.y * 32;
  const int tx = threadIdx.x & 31;
  const int ty = threadIdx.x >> 5;
#pragma unroll
  for (int r = 0; r < 4; ++r) t[ty + 8 * r][tx] = src[(size_t)(k0 + ty + 8 * r) * 256 + n0 + tx];
  __syncthreads();
#pragma unroll
  for (int r = 0; r < 4; ++r) dst[(size_t)(n0 + ty + 8 * r) * K + k0 + tx] = f2b(t[tx][ty + 8 * r]);
}

// ---------------- aggregation: S=self+neighbors (bf16), hd=deg*self (bf16), degf ----------------
__global__ __launch_bounds__(256) void k_aggregate(const ushort* __restrict__ h, const int* __restrict__ rowptr,
                                                   const int* __restrict__ col, ushort* __restrict__ S,
                                                   ushort* __restrict__ hd, float* __restrict__ degf, int n) {
  int node = blockIdx.x * 4 + (threadIdx.x >> 6);
  if (node >= n) return;
  int lane = threadIdx.x & 63;
  const ushort4* h4 = (const ushort4*)h;
  size_t base = (size_t)node * 64 + lane;
  ushort4 self = h4[base];
  float a0 = b2f(self.x), a1 = b2f(self.y), a2 = b2f(self.z), a3 = b2f(self.w);
  float s0 = a0, s1 = a1, s2 = a2, s3 = a3;
  int beg = rowptr[node], end = rowptr[node + 1];
  int p = beg;
  for (; p + 4 <= end; p += 4) {
    int j0 = col[p], j1 = col[p + 1], j2 = col[p + 2], j3 = col[p + 3];
    ushort4 v0 = h4[(size_t)j0 * 64 + lane];
    ushort4 v1 = h4[(size_t)j1 * 64 + lane];
    ushort4 v2 = h4[(size_t)j2 * 64 + lane];
    ushort4 v3 = h4[(size_t)j3 * 64 + lane];
    s0 += b2f(v0.x) + b2f(v1.x) + b2f(v2.x) + b2f(v3.x);
    s1 += b2f(v0.y) + b2f(v1.y) + b2f(v2.y) + b2f(v3.y);
    s2 += b2f(v0.z) + b2f(v1.z) + b2f(v2.z) + b2f(v3.z);
    s3 += b2f(v0.w) + b2f(v1.w) + b2f(v2.w) + b2f(v3.w);
  }
  for (; p < end; ++p) {
    int j = col[p];
    ushort4 v = h4[(size_t)j * 64 + lane];
    s0 += b2f(v.x); s1 += b2f(v.y); s2 += b2f(v.z); s3 += b2f(v.w);
  }
  float deg = (float)(end - beg + 1);
  ushort4 so; so.x = f2b(s0); so.y = f2b(s1); so.z = f2b(s2); so.w = f2b(s3);
  ((ushort4*)S)[base] = so;
  ushort4 ho; ho.x = f2b(deg * a0); ho.y = f2b(deg * a1); ho.z = f2b(deg * a2); ho.w = f2b(deg * a3);
  ((ushort4*)hd)[base] = ho;
  if (lane == 0) degf[node] = deg;
}

// ---------------- fused multi-layer MLP: round-13 two-barrier step + DEPTH-2 counted prefetch ----------------
// Triple buffers (gs%3). Prologue stages steps 0,1. Each step gs stages gs+2, then waits
// vmcnt(loads(gs+1)+loads(gs+2)) -- step-gs's loads are the oldest, two newer steps stay in
// flight (m201 "counted, never 0 in steady state" pattern). loads(s)=5 in layer 0 (1A+4B),
// 4 after (B only). All steps fully unrolled -> every count is a literal.
// Step body identical to verified round-13: wait -> s_barrier -> ds_read/MFMA(setprio) ->
// lgkmcnt(0) -> s_barrier. Layer boundaries keep __syncthreads (one vmcnt drain per layer;
// post-sync waits become no-ops until the pipeline refills -- counting stays conservative).
struct MLPArgs {
  const ushort* A0;
  const ushort* A1;        // second A for dual layer-0 (or null)
  const ushort* W0b;       // second-pass B base for layer 0 (or null)
  const ushort* W[5];
  const float* bias[5];
  const float* degf;       // rowscale for layer-0 bias (DUAL only)
  ushort* out;
  int ldw0;
  int actf[5];
};

template <int NL, int K0, bool DUAL>
__global__ __launch_bounds__(256, 2) void k_mlp(MLPArgs args, int M) {
  constexpr int KS0 = K0 >> 5;
  constexpr int NT0 = (DUAL ? 2 : 1) * KS0;
  constexpr int TOTAL = NT0 + 8 * (NL - 1);

  __shared__ ushort act[8 * 32 * 32];                 // 16 KB, chunked+swizzled
  __shared__ __align__(16) ushort As[3][32 * 32];     // 6 KB
  __shared__ __align__(16) ushort Bs[3][256 * 32];    // 48 KB

  const int m0 = blockIdx.x * 32;
  const int tid = threadIdx.x;
  const int lane = tid & 63;
  const int wn = tid >> 6;   // 0..3 : cols [wn*64, +64)
  const int rl = lane & 15;
  const int kg = lane >> 4;

  // ---- preload bias/deg into registers; drain vmcnt so counted region stays exact ----
  float biasv[NL][4];
#pragma unroll
  for (int L = 0; L < NL; ++L)
#pragma unroll
    for (int fn = 0; fn < 4; ++fn)
      biasv[L][fn] = args.bias[L][wn * 64 + fn * 16 + rl];
  float degv[8];
#pragma unroll
  for (int i = 0; i < 8; ++i) degv[i] = 1.0f;
  if (DUAL) {
#pragma unroll
    for (int fm = 0; fm < 2; ++fm)
#pragma unroll
      for (int rg = 0; rg < 4; ++rg)
        degv[fm * 4 + rg] = args.degf[m0 + fm * 16 + kg * 4 + rg];
  }
  __builtin_amdgcn_sched_barrier(0);
  asm volatile("s_waitcnt vmcnt(0)" ::: "memory");
  __builtin_amdgcn_sched_barrier(0);

  // staging slot math (verified). A: slots 0..127 duplicated for tid>=128 (uniform 1 A-load).
  const int sa_slot = tid & 127;
  const int a_row = sa_slot >> 2;
  const int a_kg = (sa_slot & 3) ^ ((a_row >> 1) & 3);
  const int s_row = tid >> 2;
  const int s_sl = tid & 3;
  int ga = m0 + a_row; if (ga > M - 1) ga = M - 1;

  auto stageA = [&](int buf, const ushort* Ap, int k0s) {
    const ushort* src = Ap + (size_t)ga * K0 + k0s + a_kg * 8;
    __builtin_amdgcn_global_load_lds(
        (const __attribute__((address_space(1))) void*)src,
        (__attribute__((address_space(3))) void*)&As[buf][sa_slot * 8], 16, 0, 0);
  };
  auto stageB = [&](int buf, const ushort* Wp, int ldw, int k0s) {
#pragma unroll
    for (int i = 0; i < 4; ++i) {
      int row = s_row + 64 * i;
      int kgi = s_sl ^ ((row >> 1) & 3);
      const ushort* src = Wp + (size_t)row * ldw + k0s + kgi * 8;
      __builtin_amdgcn_global_load_lds(
          (const __attribute__((address_space(1))) void*)src,
          (__attribute__((address_space(3))) void*)&Bs[buf][(tid + 256 * i) * 8], 16, 0, 0);
    }
  };
  // stage for global step s (compile-time after unroll)
  auto stage_step = [&](int s) {
    if (s < NT0) {
      const int pass = DUAL ? (s >= KS0 ? 1 : 0) : 0;
      const int k0s = (s & (KS0 - 1)) << 5;
      stageA(s % 3, (DUAL && pass) ? args.A1 : args.A0, k0s);
      stageB(s % 3, (DUAL && pass) ? args.W0b : args.W[0], args.ldw0, k0s);
    } else {
      const int q = s - NT0;
      stageB(s % 3, args.W[1 + (q >> 3)], 256, (q & 7) << 5);
    }
  };

  // fragment addressing precompute
  int rr_[2], sA_[2], rn_[4], sB_[4];
#pragma unroll
  for (int fm = 0; fm < 2; ++fm) {
    rr_[fm] = fm * 16 + rl;
    sA_[fm] = kg ^ ((rr_[fm] >> 1) & 3);
  }
#pragma unroll
  for (int fn = 0; fn < 4; ++fn) {
    rn_[fn] = wn * 64 + fn * 16 + rl;
    sB_[fn] = kg ^ ((rn_[fn] >> 1) & 3);
  }

  f32x4 acc[2][4];
#pragma unroll
  for (int i = 0; i < 2; ++i)
#pragma unroll
    for (int j = 0; j < 4; ++j) acc[i][j] = (f32x4)(0.f);

  auto epilogue = [&](bool useDeg, int af_, bool toGlobal,
                      float bv0, float bv1, float bv2, float bv3) {
    float bvs[4] = {bv0, bv1, bv2, bv3};
#pragma unroll
    for (int fn = 0; fn < 4; ++fn) {
      int c = wn * 64 + fn * 16 + rl;
      float bv = bvs[fn];
      int ch = c >> 5, g = (c >> 3) & 3, e = c & 7;
#pragma unroll
      for (int fm = 0; fm < 2; ++fm) {
        int lrow0 = fm * 16 + kg * 4;
#pragma unroll
        for (int rg = 0; rg < 4; ++rg) {
          int lrow = lrow0 + rg;
          float rs = useDeg ? degv[fm * 4 + rg] : 1.0f;
          float v = acc[fm][fn][rg] + rs * bv;
          if (af_) v = leaky(v);
          if (toGlobal) {
            args.out[(size_t)(m0 + lrow) * 256 + c] = f2b(v);
          } else {
            int slot = g ^ ((lrow >> 1) & 3);
            act[ch * 1024 + lrow * 32 + slot * 8 + e] = f2b(v);
          }
        }
      }
    }
  };

  // counted wait: w is a compile-time constant after unroll -> switch folds to one s_waitcnt
  auto waitv = [&](int w) {
    __builtin_amdgcn_sched_barrier(0);
    switch (w) {
      case 0:  asm volatile("s_waitcnt vmcnt(0)"  ::: "memory"); break;
      case 4:  asm volatile("s_waitcnt vmcnt(4)"  ::: "memory"); break;
      case 5:  asm volatile("s_waitcnt vmcnt(5)"  ::: "memory"); break;
      case 8:  asm volatile("s_waitcnt vmcnt(8)"  ::: "memory"); break;
      case 9:  asm volatile("s_waitcnt vmcnt(9)"  ::: "memory"); break;
      default: asm volatile("s_waitcnt vmcnt(10)" ::: "memory"); break;
    }
    __builtin_amdgcn_sched_barrier(0);
  };

  // ---------- depth-2 pipeline over all layers ----------
  stage_step(0);
  stage_step(1);

#pragma unroll
  for (int gs = 0; gs < TOTAL; ++gs) {
    if (gs + 2 < TOTAL) stage_step(gs + 2);
    {
      const int l1 = (gs + 1 < TOTAL) ? ((gs + 1 < NT0) ? 5 : 4) : 0;
      const int l2 = (gs + 2 < TOTAL) ? ((gs + 2 < NT0) ? 5 : 4) : 0;
      waitv(l1 + l2);
    }
    __builtin_amdgcn_s_barrier();          // #1: all waves' stage-gs landed
    __builtin_amdgcn_sched_barrier(0);
    {
      const ushort* bB = &Bs[gs % 3][0];
      bf16x8 afr[2], bfr[4];
      if (gs < NT0) {
        const ushort* bA = &As[gs % 3][0];
#pragma unroll
        for (int fm = 0; fm < 2; ++fm) afr[fm] = *(const bf16x8*)&bA[rr_[fm] * 32 + sA_[fm] * 8];
      } else {
        const int tloc = (gs - NT0) & 7;
#pragma unroll
        for (int fm = 0; fm < 2; ++fm)
          afr[fm] = *(const bf16x8*)&act[tloc * 1024 + rr_[fm] * 32 + sA_[fm] * 8];
      }
#pragma unroll
      for (int fn = 0; fn < 4; ++fn) bfr[fn] = *(const bf16x8*)&bB[rn_[fn] * 32 + sB_[fn] * 8];
      __builtin_amdgcn_s_setprio(1);
#pragma unroll
      for (int fm = 0; fm < 2; ++fm)
#pragma unroll
        for (int fn = 0; fn < 4; ++fn)
          acc[fm][fn] = __builtin_amdgcn_mfma_f32_16x16x32_bf16(afr[fm], bfr[fn], acc[fm][fn], 0, 0, 0);
      __builtin_amdgcn_s_setprio(0);
    }
    __builtin_amdgcn_sched_barrier(0);
    asm volatile("s_waitcnt lgkmcnt(0)" ::: "memory");  // this wave's ds_reads retired
    __builtin_amdgcn_sched_barrier(0);
    __builtin_amdgcn_s_barrier();          // #2: buf gs%3 safe to overwrite

    // layer boundary?
    const bool lend = (gs < NT0) ? (gs == NT0 - 1) : (((gs - NT0) & 7) == 7);
    if (lend) {
      const int Lc = (gs < NT0) ? 0 : 1 + ((gs - NT0) >> 3);
      if (Lc == NL - 1) {
        epilogue(DUAL && Lc == 0, args.actf[Lc], true,
                 biasv[Lc][0], biasv[Lc][1], biasv[Lc][2], biasv[Lc][3]);
      } else {
        epilogue(DUAL && Lc == 0, args.actf[Lc], false,
                 biasv[Lc][0], biasv[Lc][1], biasv[Lc][2], biasv[Lc][3]);
        __syncthreads();  // act visible (one vmcnt drain per layer)
#pragma unroll
        for (int i = 0; i < 2; ++i)
#pragma unroll
          for (int j = 0; j < 4; ++j) acc[i][j] = (f32x4)(0.f);
      }
    }
  }
}

// ---------------- decoder layer ----------------
__global__ __launch_bounds__(256) void k_dec_layer(
    const float* __restrict__ A, const float* __restrict__ W,
    const float* __restrict__ bias, float* __restrict__ out,
    int K, int N, int act)
{
  __shared__ float a[768];
  __shared__ float red[8][64];
  const int g = blockIdx.y;
  const int cols = (N >= 64) ? 64 : 32;
  const int segs = 256 / cols;
  const int t = threadIdx.x;
  const int col = t % cols, seg = t / cols;
  const int c = blockIdx.x * cols + col;
  for (int i = t; i < K; i += 256) a[i] = A[(size_t)g * K + i];
  __syncthreads();
  const int kper = K / segs;
  const int k0 = seg * kper;
  float p = 0.f;
#pragma unroll 8
  for (int k = k0; k < k0 + kper; ++k) p += a[k] * W[(size_t)k * N + c];
  red[seg][col] = p;
  __syncthreads();
  if (seg == 0) {
    float s = bias[c];
    for (int i = 0; i < segs; ++i) s += red[i][col];
    out[(size_t)g * N + c] = act ? leaky(s) : s;
  }
}

// ---------------- pooling ----------------
__global__ __launch_bounds__(256) void k_pool1(const ushort* __restrict__ h, const int* __restrict__ gstart,
                                               const int* __restrict__ gcnt, float* __restrict__ psum,
                                               float* __restrict__ pmax) {
  int g = blockIdx.x >> 4;
  int cch = blockIdx.x & 15;
  int t = threadIdx.x;
  int len = gcnt[g];
  int s0 = gstart[g];
  int chunk = (len + 15) >> 4;
  int i0 = s0 + cch * chunk;
  int i1 = min(i0 + chunk, s0 + len);
  float s = 0.f;
  float m = -3.402823466e+38f;
  for (int i = i0; i < i1; ++i) {
    float v = b2f(h[(size_t)i * HID + t]);
    s += v;
    m = fmaxf(m, v);
  }
  psum[(size_t)blockIdx.x * HID + t] = s;
  pmax[(size_t)blockIdx.x * HID + t] = m;
}

__global__ __launch_bounds__(256) void k_pool2(const float* __restrict__ psum, const float* __restrict__ pmax,
                                               const int* __restrict__ gcnt, float* __restrict__ pooled) {
  int g = blockIdx.x;
  int t = threadIdx.x;
  float s = 0.f, m = -3.402823466e+38f;
  for (int cch = 0; cch < 16; ++cch) {
    s += psum[(size_t)(g * 16 + cch) * HID + t];
    m = fmaxf(m, pmax[(size_t)(g * 16 + cch) * HID + t]);
  }
  float cf = (float)gcnt[g];
  pooled[g * 3 * HID + t] = s / fmaxf(cf, 1.f);
  pooled[g * 3 * HID + HID + t] = m;
  pooled[g * 3 * HID + 2 * HID + t] = s;
}

// ---------------- launch ----------------
extern "C" void kernel_launch(void* const* d_in, const int* in_sizes, int n_in,
                              void* d_out, int out_size, void* d_ws, size_t ws_size,
                              hipStream_t stream) {
  const float* x        = (const float*)d_in[0];
  const int*   ei       = (const int*)d_in[1];
  const int*   batch    = (const int*)d_in[2];
  const float* enc_Win  = (const float*)d_in[3];
  const float* enc_bin  = (const float*)d_in[4];
  const float* enc_Wh   = (const float*)d_in[5];
  const float* enc_bh   = (const float*)d_in[6];
  const float* enc_Wout = (const float*)d_in[7];
  const float* enc_bout = (const float*)d_in[8];
  const float* edge_W   = (const float*)d_in[9];
  const float* edge_b   = (const float*)d_in[10];
  const float* proc_Win = (const float*)d_in[11];
  const float* proc_bin = (const float*)d_in[12];
  const float* proc_Wh  = (const float*)d_in[13];
  const float* proc_bh  = (const float*)d_in[14];
  const float* proc_Wout= (const float*)d_in[15];
  const float* proc_bout= (const float*)d_in[16];
  const float* dec_Win  = (const float*)d_in[17];
  const float* dec_bin  = (const float*)d_in[18];
  const float* dec_Wh   = (const float*)d_in[19];
  const float* dec_bh   = (const float*)d_in[20];
  const float* dec_Wout = (const float*)d_in[21];
  const float* dec_bout = (const float*)d_in[22];

  const int n  = in_sizes[0] / 128;  // 20000
  const int ne = in_sizes[1] / 2;    // 160000
  const int H = HID;

  char* p = (char*)d_ws;
  auto alloc = [&](size_t bytes) -> char* {
    char* r = p;
    p += (bytes + 255) & ~(size_t)255;
    return r;
  };
  ushort* hb1   = (ushort*)alloc((size_t)n * H * 2);
  ushort* Sb    = (ushort*)alloc((size_t)n * H * 2);
  ushort* hdb   = (ushort*)alloc((size_t)n * H * 2);
  ushort* xb    = (ushort*)alloc((size_t)n * 128 * 2);
  ushort* w_enc_in  = (ushort*)alloc((size_t)256 * 128 * 2);
  ushort* w_enc_h0  = (ushort*)alloc((size_t)256 * 256 * 2);
  ushort* w_enc_h1  = (ushort*)alloc((size_t)256 * 256 * 2);
  ushort* w_enc_out = (ushort*)alloc((size_t)256 * 256 * 2);
  ushort* w_proc_in  = (ushort*)alloc((size_t)256 * 256 * 2);
  ushort* w_proc_h0  = (ushort*)alloc((size_t)256 * 256 * 2);
  ushort* w_proc_h1  = (ushort*)alloc((size_t)256 * 256 * 2);
  ushort* w_proc_out = (ushort*)alloc((size_t)256 * 256 * 2);
  ushort* w_edge     = (ushort*)alloc((size_t)256 * 512 * 2);
  float* degf   = (float*)alloc((size_t)n * 4);
  float* pooled = (float*)alloc((size_t)NGRAPH * 3 * H * 4);
  float* psum   = (float*)alloc((size_t)256 * H * 4);
  float* pmax   = (float*)alloc((size_t)256 * H * 4);
  float* db0    = (float*)alloc((size_t)NGRAPH * H * 4);
  float* db1    = (float*)alloc((size_t)NGRAPH * H * 4);
  int* cnt    = (int*)alloc((size_t)n * 4);
  int* rowptr = (int*)alloc((size_t)(n + 1) * 4);
  int* cursor = (int*)alloc((size_t)n * 4);
  int* gstart = (int*)alloc((size_t)(NGRAPH + 1) * 4);
  int* gcnt   = (int*)alloc((size_t)NGRAPH * 4);
  int* colv   = (int*)alloc((size_t)ne * 4);

  const int* srcI = ei;
  const int* dstI = ei + ne;

  dim3 blk(256);

  // fused weight conversions (transpose to [N=256][K] bf16)
  WconvArgs wa;
  wa.src[0] = enc_Win;             wa.dst[0] = w_enc_in;   wa.K[0] = 128;
  wa.src[1] = enc_Wh;              wa.dst[1] = w_enc_h0;   wa.K[1] = 256;
  wa.src[2] = enc_Wh + 65536;      wa.dst[2] = w_enc_h1;   wa.K[2] = 256;
  wa.src[3] = enc_Wout;            wa.dst[3] = w_enc_out;  wa.K[3] = 256;
  wa.src[4] = proc_Win;            wa.dst[4] = w_proc_in;  wa.K[4] = 256;
  wa.src[5] = proc_Wh;             wa.dst[5] = w_proc_h0;  wa.K[5] = 256;
  wa.src[6] = proc_Wh + 65536;     wa.dst[6] = w_proc_h1;  wa.K[6] = 256;
  wa.src[7] = proc_Wout;           wa.dst[7] = w_proc_out; wa.K[7] = 256;
  wa.src[8] = edge_W;              wa.dst[8] = w_edge;     wa.K[8] = 512;
  k_wconv_all<<<dim3(16, 8, 9), blk, 0, stream>>>(wa);
  k_f2b<<<dim3((n * 128 / 4 + 255) / 256), blk, 0, stream>>>(x, xb, n * 128);

  // CSR by destination + per-graph bounds
  k_zero_i32<<<dim3((n + 255) / 256), blk, 0, stream>>>(cnt, n);
  k_hist<<<dim3((ne + 255) / 256), blk, 0, stream>>>(dstI, cnt, ne);
  k_scan<<<1, 1024, 0, stream>>>(cnt, rowptr, cursor, n);
  k_gbounds<<<1, 64, 0, stream>>>(batch, n, gstart, gcnt);
  k_scatter<<<dim3((ne + 255) / 256), blk, 0, stream>>>(srcI, dstI, cursor, colv, ne);

  const int npanel = (n + 31) / 32;  // 625 (20000 = 625*32 exactly)

  // fused encoder: 4 layers, one kernel
  MLPArgs ea = {};
  ea.A0 = xb; ea.A1 = nullptr; ea.W0b = nullptr;
  ea.W[0] = w_enc_in; ea.W[1] = w_enc_h0; ea.W[2] = w_enc_h1; ea.W[3] = w_enc_out;
  ea.bias[0] = enc_bin; ea.bias[1] = enc_bh; ea.bias[2] = enc_bh + 256; ea.bias[3] = enc_bout;
  ea.bias[4] = enc_bout;  // unused slot, keep valid pointer
  ea.degf = nullptr; ea.out = hb1; ea.ldw0 = 128;
  ea.actf[0] = 1; ea.actf[1] = 1; ea.actf[2] = 1; ea.actf[3] = 0;
  k_mlp<4, 128, false><<<dim3(npanel), blk, 0, stream>>>(ea, n);

  // fused proc: edge (dual-A) + 4 proc layers, one kernel per MP round
  MLPArgs pa = {};
  pa.A0 = hdb; pa.A1 = Sb; pa.W0b = w_edge + 256;
  pa.W[0] = w_edge; pa.W[1] = w_proc_in; pa.W[2] = w_proc_h0; pa.W[3] = w_proc_h1; pa.W[4] = w_proc_out;
  pa.bias[0] = edge_b; pa.bias[1] = proc_bin; pa.bias[2] = proc_bh; pa.bias[3] = proc_bh + 256; pa.bias[4] = proc_bout;
  pa.degf = degf; pa.out = hb1; pa.ldw0 = 512;
  pa.actf[0] = 0; pa.actf[1] = 1; pa.actf[2] = 1; pa.actf[3] = 1; pa.actf[4] = 0;

  for (int r = 0; r < 4; ++r) {
    k_aggregate<<<dim3((n + 3) / 4), blk, 0, stream>>>(hb1, rowptr, colv, Sb, hdb, degf, n);
    k_mlp<5, 256, true><<<dim3(npanel), blk, 0, stream>>>(pa, n);
  }

  // pooling
  k_pool1<<<dim3(NGRAPH * 16), blk, 0, stream>>>(hb1, gstart, gcnt, psum, pmax);
  k_pool2<<<dim3(NGRAPH), blk, 0, stream>>>(psum, pmax, gcnt, pooled);

  // decoder
  k_dec_layer<<<dim3(4, NGRAPH), blk, 0, stream>>>(pooled, dec_Win, dec_bin, db0, 768, 256, 1);
  k_dec_layer<<<dim3(4, NGRAPH), blk, 0, stream>>>(db0, dec_Wh, dec_bh, db1, 256, 256, 1);
  k_dec_layer<<<dim3(4, NGRAPH), blk, 0, stream>>>(db1, dec_Wh + 65536, dec_bh + 256, db0, 256, 256, 1);
  k_dec_layer<<<dim3(1, NGRAPH), blk, 0, stream>>>(db0, dec_Wout, dec_bout, (float*)d_out, 256, 32, 0);
}

// Round 17
// 373.549 us; speedup vs baseline: 1.3125x; 1.3125x over previous
//
#include <hip/hip_runtime.h>
#include <hip/hip_bf16.h>
#include <cstdint>

#define HID 256
#define NGRAPH 16
#define NEG_SLOPE 0.01f

typedef __bf16 bf16x8 __attribute__((ext_vector_type(8)));
typedef float f32x4 __attribute__((ext_vector_type(4)));

__device__ __forceinline__ float leaky(float x) { return x >= 0.f ? x : NEG_SLOPE * x; }

__device__ __forceinline__ ushort f2b(float f) {
  uint u = __float_as_uint(f);
  uint r = (u + 0x7fffu + ((u >> 16) & 1u)) >> 16;
  return (ushort)r;
}
__device__ __forceinline__ float b2f(ushort b) { return __uint_as_float((uint)b << 16); }

// ---------------- CSR build ----------------
__global__ __launch_bounds__(256) void k_zero_i32(int* p, int n) {
  int i = blockIdx.x * blockDim.x + threadIdx.x;
  if (i < n) p[i] = 0;
}

__global__ __launch_bounds__(256) void k_hist(const int* __restrict__ key, int* __restrict__ cnt, int ne) {
  int e = blockIdx.x * blockDim.x + threadIdx.x;
  if (e < ne) atomicAdd(&cnt[key[e]], 1);
}

__global__ __launch_bounds__(1024) void k_scan(const int* __restrict__ cnt, int* __restrict__ rowptr,
                                               int* __restrict__ cursor, int n) {
  __shared__ int sd[1024];
  int tid = threadIdx.x;
  int CH = n / 1024 + 1;
  int base = tid * CH;
  int s = 0;
  for (int i = 0; i < CH; ++i) { int idx = base + i; if (idx < n) s += cnt[idx]; }
  sd[tid] = s;
  __syncthreads();
  for (int off = 1; off < 1024; off <<= 1) {
    int v = (tid >= off) ? sd[tid - off] : 0;
    __syncthreads();
    sd[tid] += v;
    __syncthreads();
  }
  int run = (tid == 0) ? 0 : sd[tid - 1];
  for (int i = 0; i < CH; ++i) {
    int idx = base + i;
    if (idx <= n) {
      rowptr[idx] = run;
      if (idx < n) { cursor[idx] = run; run += cnt[idx]; }
    }
  }
}

// batch sorted -> per-graph bounds via binary search
__global__ __launch_bounds__(64) void k_gbounds(const int* __restrict__ batch, int n,
                                                int* __restrict__ gstart, int* __restrict__ gcnt) {
  int t = threadIdx.x;
  if (t <= NGRAPH) {
    int lo = 0, hi = n;
    while (lo < hi) { int mid = (lo + hi) >> 1; if (batch[mid] < t) lo = mid + 1; else hi = mid; }
    gstart[t] = lo;
  }
  __syncthreads();
  if (t < NGRAPH) gcnt[t] = gstart[t + 1] - gstart[t];
}

__global__ __launch_bounds__(256) void k_scatter(const int* __restrict__ src, const int* __restrict__ dst,
                                                 int* __restrict__ cursor, int* __restrict__ col, int ne) {
  int e = blockIdx.x * blockDim.x + threadIdx.x;
  if (e < ne) {
    int d = dst[e];
    int pos = atomicAdd(&cursor[d], 1);
    col[pos] = src[e];
  }
}

// ---------------- conversions ----------------
__global__ __launch_bounds__(256) void k_f2b(const float* __restrict__ src, ushort* __restrict__ dst, int nElem) {
  int i = (blockIdx.x * 256 + threadIdx.x) * 4;
  if (i + 3 < nElem) {
    float4 v = *(const float4*)&src[i];
    ushort4 o;
    o.x = f2b(v.x); o.y = f2b(v.y); o.z = f2b(v.z); o.w = f2b(v.w);
    *(ushort4*)&dst[i] = o;
  } else {
    for (int j = i; j < nElem; ++j) dst[j] = f2b(src[j]);
  }
}

// fused transpose-convert: dst[n][k] = bf16(src[k][n]); src is [K][256]
struct WconvArgs {
  const float* src[9];
  ushort* dst[9];
  int K[9];
};

__global__ __launch_bounds__(256) void k_wconv_all(WconvArgs args) {
  __shared__ float t[32][33];
  const int e = blockIdx.z;
  const int K = args.K[e];
  const int k0 = blockIdx.x * 32;
  if (k0 >= K) return;
  const float* src = args.src[e];
  ushort* dst = args.dst[e];
  const int n0 = blockIdx.y * 32;
  const int tx = threadIdx.x & 31;
  const int ty = threadIdx.x >> 5;
#pragma unroll
  for (int r = 0; r < 4; ++r) t[ty + 8 * r][tx] = src[(size_t)(k0 + ty + 8 * r) * 256 + n0 + tx];
  __syncthreads();
#pragma unroll
  for (int r = 0; r < 4; ++r) dst[(size_t)(n0 + ty + 8 * r) * K + k0 + tx] = f2b(t[tx][ty + 8 * r]);
}

// ---------------- aggregation v2: half-wave (32 lanes x 16B) per node ----------------
// 8 nodes/block -> 2x independent gather chains per CU vs v1. Same CSR order + f32
// accumulation per column -> bitwise-identical results to v1.
__device__ __forceinline__ void acc8(float* s, uint4 v) {
  s[0] += b2f((ushort)(v.x & 0xffff)); s[1] += b2f((ushort)(v.x >> 16));
  s[2] += b2f((ushort)(v.y & 0xffff)); s[3] += b2f((ushort)(v.y >> 16));
  s[4] += b2f((ushort)(v.z & 0xffff)); s[5] += b2f((ushort)(v.z >> 16));
  s[6] += b2f((ushort)(v.w & 0xffff)); s[7] += b2f((ushort)(v.w >> 16));
}

__global__ __launch_bounds__(256) void k_aggregate(const ushort* __restrict__ h, const int* __restrict__ rowptr,
                                                   const int* __restrict__ col, ushort* __restrict__ S,
                                                   ushort* __restrict__ hd, float* __restrict__ degf, int n) {
  int node = blockIdx.x * 8 + (threadIdx.x >> 5);
  if (node >= n) return;
  int lane = threadIdx.x & 31;
  const uint4* h16 = (const uint4*)h;  // 8 bf16 per lane = 16B; 32 lanes = 512B row
  size_t base = (size_t)node * 32 + lane;
  uint4 self = h16[base];
  float a[8] = {0, 0, 0, 0, 0, 0, 0, 0};
  acc8(a, self);
  float s[8];
#pragma unroll
  for (int i = 0; i < 8; ++i) s[i] = a[i];
  int beg = rowptr[node], end = rowptr[node + 1];
  int p = beg;
  for (; p + 4 <= end; p += 4) {
    int j0 = col[p], j1 = col[p + 1], j2 = col[p + 2], j3 = col[p + 3];
    uint4 v0 = h16[(size_t)j0 * 32 + lane];
    uint4 v1 = h16[(size_t)j1 * 32 + lane];
    uint4 v2 = h16[(size_t)j2 * 32 + lane];
    uint4 v3 = h16[(size_t)j3 * 32 + lane];
    acc8(s, v0); acc8(s, v1); acc8(s, v2); acc8(s, v3);
  }
  for (; p < end; ++p) {
    int j = col[p];
    uint4 v = h16[(size_t)j * 32 + lane];
    acc8(s, v);
  }
  float deg = (float)(end - beg + 1);
  uint4 so;
  so.x = (uint)f2b(s[0]) | ((uint)f2b(s[1]) << 16);
  so.y = (uint)f2b(s[2]) | ((uint)f2b(s[3]) << 16);
  so.z = (uint)f2b(s[4]) | ((uint)f2b(s[5]) << 16);
  so.w = (uint)f2b(s[6]) | ((uint)f2b(s[7]) << 16);
  ((uint4*)S)[base] = so;
  uint4 ho;
  ho.x = (uint)f2b(deg * a[0]) | ((uint)f2b(deg * a[1]) << 16);
  ho.y = (uint)f2b(deg * a[2]) | ((uint)f2b(deg * a[3]) << 16);
  ho.z = (uint)f2b(deg * a[4]) | ((uint)f2b(deg * a[5]) << 16);
  ho.w = (uint)f2b(deg * a[6]) | ((uint)f2b(deg * a[7]) << 16);
  ((uint4*)hd)[base] = ho;
  if (lane == 0) degf[node] = deg;
}

// ---------------- fused multi-layer MLP, counted-vmcnt + two light s_barriers per step ----------------
// (verbatim round-13 verified structure, 46.6 us/dispatch)
struct MLPArgs {
  const ushort* A0;
  const ushort* A1;        // second A for dual layer-0 (or null)
  const ushort* W0b;       // second-pass B base for layer 0 (or null)
  const ushort* W[5];
  const float* bias[5];
  const float* degf;       // rowscale for layer-0 bias (DUAL only)
  ushort* out;
  int ldw0;
  int actf[5];
};

template <int NL, int K0, bool DUAL>
__global__ __launch_bounds__(256, 2) void k_mlp(MLPArgs args, int M) {
  constexpr int KS0 = K0 >> 5;
  constexpr int NT0 = (DUAL ? 2 : 1) * KS0;

  __shared__ ushort act[8 * 32 * 32];                 // 16 KB, chunked+swizzled
  __shared__ __align__(16) ushort As[2][32 * 32];     // 4 KB
  __shared__ __align__(16) ushort Bs[2][256 * 32];    // 32 KB

  const int m0 = blockIdx.x * 32;
  const int tid = threadIdx.x;
  const int lane = tid & 63;
  const int wn = tid >> 6;   // 0..3 : cols [wn*64, +64)
  const int rl = lane & 15;
  const int kg = lane >> 4;

  // ---- preload bias/deg into registers; drain vmcnt so counted region stays exact ----
  float biasv[NL][4];
#pragma unroll
  for (int L = 0; L < NL; ++L)
#pragma unroll
    for (int fn = 0; fn < 4; ++fn)
      biasv[L][fn] = args.bias[L][wn * 64 + fn * 16 + rl];
  float degv[8];
#pragma unroll
  for (int i = 0; i < 8; ++i) degv[i] = 1.0f;
  if (DUAL) {
#pragma unroll
    for (int fm = 0; fm < 2; ++fm)
#pragma unroll
      for (int rg = 0; rg < 4; ++rg)
        degv[fm * 4 + rg] = args.degf[m0 + fm * 16 + kg * 4 + rg];
  }
  __builtin_amdgcn_sched_barrier(0);
  asm volatile("s_waitcnt vmcnt(0)" ::: "memory");
  __builtin_amdgcn_sched_barrier(0);

  // staging slot math. A: slots 0..127, duplicated for tid>=128 (uniform 1 A-load/thread).
  const int sa_slot = tid & 127;
  const int a_row = sa_slot >> 2;
  const int a_kg = (sa_slot & 3) ^ ((a_row >> 1) & 3);
  const int s_row = tid >> 2;
  const int s_sl = tid & 3;
  int ga = m0 + a_row; if (ga > M - 1) ga = M - 1;

  auto stageA = [&](int buf, const ushort* Ap, int k0s) {
    const ushort* src = Ap + (size_t)ga * K0 + k0s + a_kg * 8;
    __builtin_amdgcn_global_load_lds(
        (const __attribute__((address_space(1))) void*)src,
        (__attribute__((address_space(3))) void*)&As[buf][sa_slot * 8], 16, 0, 0);
  };
  auto stageB = [&](int buf, const ushort* Wp, int ldw, int k0s) {
#pragma unroll
    for (int i = 0; i < 4; ++i) {
      int row = s_row + 64 * i;
      int kgi = s_sl ^ ((row >> 1) & 3);
      const ushort* src = Wp + (size_t)row * ldw + k0s + kgi * 8;
      __builtin_amdgcn_global_load_lds(
          (const __attribute__((address_space(1))) void*)src,
          (__attribute__((address_space(3))) void*)&Bs[buf][(tid + 256 * i) * 8], 16, 0, 0);
    }
  };

  // fragment addressing precompute
  int rr_[2], sA_[2], rn_[4], sB_[4];
#pragma unroll
  for (int fm = 0; fm < 2; ++fm) {
    rr_[fm] = fm * 16 + rl;
    sA_[fm] = kg ^ ((rr_[fm] >> 1) & 3);
  }
#pragma unroll
  for (int fn = 0; fn < 4; ++fn) {
    rn_[fn] = wn * 64 + fn * 16 + rl;
    sB_[fn] = kg ^ ((rn_[fn] >> 1) & 3);
  }

  f32x4 acc[2][4];

  auto epilogue = [&](bool useDeg, int af_, bool toGlobal,
                      float bv0, float bv1, float bv2, float bv3) {
    float bvs[4] = {bv0, bv1, bv2, bv3};
#pragma unroll
    for (int fn = 0; fn < 4; ++fn) {
      int c = wn * 64 + fn * 16 + rl;
      float bv = bvs[fn];
      int ch = c >> 5, g = (c >> 3) & 3, e = c & 7;
#pragma unroll
      for (int fm = 0; fm < 2; ++fm) {
        int lrow0 = fm * 16 + kg * 4;
#pragma unroll
        for (int rg = 0; rg < 4; ++rg) {
          int lrow = lrow0 + rg;
          float rs = useDeg ? degv[fm * 4 + rg] : 1.0f;
          float v = acc[fm][fn][rg] + rs * bv;
          if (af_) v = leaky(v);
          if (toGlobal) {
            args.out[(size_t)(m0 + lrow) * 256 + c] = f2b(v);
          } else {
            int slot = g ^ ((lrow >> 1) & 3);
            act[ch * 1024 + lrow * 32 + slot * 8 + e] = f2b(v);
          }
        }
      }
    }
  };

#define WAITV(n)                                              \
  __builtin_amdgcn_sched_barrier(0);                          \
  asm volatile("s_waitcnt vmcnt(" #n ")" ::: "memory");       \
  __builtin_amdgcn_sched_barrier(0);
#define READS_DONE                                            \
  __builtin_amdgcn_sched_barrier(0);                          \
  asm volatile("s_waitcnt lgkmcnt(0)" ::: "memory");          \
  __builtin_amdgcn_sched_barrier(0);

  // ---------- layer 0: A+B staged from global ----------
#pragma unroll
  for (int i = 0; i < 2; ++i)
#pragma unroll
    for (int j = 0; j < 4; ++j) acc[i][j] = (f32x4)(0.f);

  stageA(0, args.A0, 0);
  stageB(0, args.W[0], args.ldw0, 0);   // 5 outstanding

#pragma unroll
  for (int t = 0; t < NT0; ++t) {
    if (t + 1 < NT0) {
      const int tp = t + 1;
      const int pass = DUAL ? (tp >= KS0 ? 1 : 0) : 0;
      const int k0s = (tp - pass * KS0) << 5;
      stageA(tp & 1, pass ? args.A1 : args.A0, k0s);
      stageB(tp & 1, pass ? args.W0b : args.W[0], args.ldw0, k0s);
      WAITV(5)
    } else if (NL > 1) {
      stageB(0, args.W[1], 256, 0);
      WAITV(4)
    } else {
      WAITV(0)
    }
    __builtin_amdgcn_s_barrier();          // #1: all waves' stage-t landed
    __builtin_amdgcn_sched_barrier(0);
    {
      const ushort* bA = &As[t & 1][0];
      const ushort* bB = &Bs[t & 1][0];
      bf16x8 afr[2], bfr[4];
#pragma unroll
      for (int fm = 0; fm < 2; ++fm) afr[fm] = *(const bf16x8*)&bA[rr_[fm] * 32 + sA_[fm] * 8];
#pragma unroll
      for (int fn = 0; fn < 4; ++fn) bfr[fn] = *(const bf16x8*)&bB[rn_[fn] * 32 + sB_[fn] * 8];
      __builtin_amdgcn_s_setprio(1);
#pragma unroll
      for (int fm = 0; fm < 2; ++fm)
#pragma unroll
        for (int fn = 0; fn < 4; ++fn)
          acc[fm][fn] = __builtin_amdgcn_mfma_f32_16x16x32_bf16(afr[fm], bfr[fn], acc[fm][fn], 0, 0, 0);
      __builtin_amdgcn_s_setprio(0);
    }
    READS_DONE                             // this wave's ds_reads of buf[t&1] retired
    __builtin_amdgcn_s_barrier();          // #2: buf[t&1] safe to overwrite next step
  }
  if (NL == 1) {
    epilogue(DUAL, args.actf[0], true, biasv[0][0], biasv[0][1], biasv[0][2], biasv[0][3]);
  } else {
    epilogue(DUAL, args.actf[0], false, biasv[0][0], biasv[0][1], biasv[0][2], biasv[0][3]);
    __syncthreads();  // act visible (drains the 4 prefetched loads - once per layer)
  }

  // ---------- layers 1..NL-1: A from act LDS, B staged ----------
#pragma unroll
  for (int L = 1; L < NL; ++L) {
#pragma unroll
    for (int i = 0; i < 2; ++i)
#pragma unroll
      for (int j = 0; j < 4; ++j) acc[i][j] = (f32x4)(0.f);
    // step-0 B was prefetched at the end of the previous layer (drained by __syncthreads)
#pragma unroll
    for (int t = 0; t < 8; ++t) {
      if (t < 7) {
        stageB((t + 1) & 1, args.W[L], 256, (t + 1) * 32);
        WAITV(4)
      } else if (L + 1 < NL) {
        stageB(0, args.W[L + 1], 256, 0);
        WAITV(4)
      } else {
        WAITV(0)
      }
      __builtin_amdgcn_s_barrier();        // #1
      __builtin_amdgcn_sched_barrier(0);
      {
        const ushort* bB = &Bs[t & 1][0];
        bf16x8 afr[2], bfr[4];
#pragma unroll
        for (int fm = 0; fm < 2; ++fm)
          afr[fm] = *(const bf16x8*)&act[t * 1024 + rr_[fm] * 32 + sA_[fm] * 8];
#pragma unroll
        for (int fn = 0; fn < 4; ++fn) bfr[fn] = *(const bf16x8*)&bB[rn_[fn] * 32 + sB_[fn] * 8];
        __builtin_amdgcn_s_setprio(1);
#pragma unroll
        for (int fm = 0; fm < 2; ++fm)
#pragma unroll
          for (int fn = 0; fn < 4; ++fn)
            acc[fm][fn] = __builtin_amdgcn_mfma_f32_16x16x32_bf16(afr[fm], bfr[fn], acc[fm][fn], 0, 0, 0);
        __builtin_amdgcn_s_setprio(0);
      }
      READS_DONE
      __builtin_amdgcn_s_barrier();        // #2
    }
    if (L == NL - 1) {
      epilogue(false, args.actf[L], true, biasv[L][0], biasv[L][1], biasv[L][2], biasv[L][3]);
    } else {
      epilogue(false, args.actf[L], false, biasv[L][0], biasv[L][1], biasv[L][2], biasv[L][3]);
      __syncthreads();  // new act visible
    }
  }
#undef WAITV
#undef READS_DONE
}

// ---------------- decoder layer ----------------
__global__ __launch_bounds__(256) void k_dec_layer(
    const float* __restrict__ A, const float* __restrict__ W,
    const float* __restrict__ bias, float* __restrict__ out,
    int K, int N, int act)
{
  __shared__ float a[768];
  __shared__ float red[8][64];
  const int g = blockIdx.y;
  const int cols = (N >= 64) ? 64 : 32;
  const int segs = 256 / cols;
  const int t = threadIdx.x;
  const int col = t % cols, seg = t / cols;
  const int c = blockIdx.x * cols + col;
  for (int i = t; i < K; i += 256) a[i] = A[(size_t)g * K + i];
  __syncthreads();
  const int kper = K / segs;
  const int k0 = seg * kper;
  float p = 0.f;
#pragma unroll 8
  for (int k = k0; k < k0 + kper; ++k) p += a[k] * W[(size_t)k * N + c];
  red[seg][col] = p;
  __syncthreads();
  if (seg == 0) {
    float s = bias[c];
    for (int i = 0; i < segs; ++i) s += red[i][col];
    out[(size_t)g * N + c] = act ? leaky(s) : s;
  }
}

// ---------------- pooling ----------------
__global__ __launch_bounds__(256) void k_pool1(const ushort* __restrict__ h, const int* __restrict__ gstart,
                                               const int* __restrict__ gcnt, float* __restrict__ psum,
                                               float* __restrict__ pmax) {
  int g = blockIdx.x >> 4;
  int cch = blockIdx.x & 15;
  int t = threadIdx.x;
  int len = gcnt[g];
  int s0 = gstart[g];
  int chunk = (len + 15) >> 4;
  int i0 = s0 + cch * chunk;
  int i1 = min(i0 + chunk, s0 + len);
  float s = 0.f;
  float m = -3.402823466e+38f;
  for (int i = i0; i < i1; ++i) {
    float v = b2f(h[(size_t)i * HID + t]);
    s += v;
    m = fmaxf(m, v);
  }
  psum[(size_t)blockIdx.x * HID + t] = s;
  pmax[(size_t)blockIdx.x * HID + t] = m;
}

__global__ __launch_bounds__(256) void k_pool2(const float* __restrict__ psum, const float* __restrict__ pmax,
                                               const int* __restrict__ gcnt, float* __restrict__ pooled) {
  int g = blockIdx.x;
  int t = threadIdx.x;
  float s = 0.f, m = -3.402823466e+38f;
  for (int cch = 0; cch < 16; ++cch) {
    s += psum[(size_t)(g * 16 + cch) * HID + t];
    m = fmaxf(m, pmax[(size_t)(g * 16 + cch) * HID + t]);
  }
  float cf = (float)gcnt[g];
  pooled[g * 3 * HID + t] = s / fmaxf(cf, 1.f);
  pooled[g * 3 * HID + HID + t] = m;
  pooled[g * 3 * HID + 2 * HID + t] = s;
}

// ---------------- launch ----------------
extern "C" void kernel_launch(void* const* d_in, const int* in_sizes, int n_in,
                              void* d_out, int out_size, void* d_ws, size_t ws_size,
                              hipStream_t stream) {
  const float* x        = (const float*)d_in[0];
  const int*   ei       = (const int*)d_in[1];
  const int*   batch    = (const int*)d_in[2];
  const float* enc_Win  = (const float*)d_in[3];
  const float* enc_bin  = (const float*)d_in[4];
  const float* enc_Wh   = (const float*)d_in[5];
  const float* enc_bh   = (const float*)d_in[6];
  const float* enc_Wout = (const float*)d_in[7];
  const float* enc_bout = (const float*)d_in[8];
  const float* edge_W   = (const float*)d_in[9];
  const float* edge_b   = (const float*)d_in[10];
  const float* proc_Win = (const float*)d_in[11];
  const float* proc_bin = (const float*)d_in[12];
  const float* proc_Wh  = (const float*)d_in[13];
  const float* proc_bh  = (const float*)d_in[14];
  const float* proc_Wout= (const float*)d_in[15];
  const float* proc_bout= (const float*)d_in[16];
  const float* dec_Win  = (const float*)d_in[17];
  const float* dec_bin  = (const float*)d_in[18];
  const float* dec_Wh   = (const float*)d_in[19];
  const float* dec_bh   = (const float*)d_in[20];
  const float* dec_Wout = (const float*)d_in[21];
  const float* dec_bout = (const float*)d_in[22];

  const int n  = in_sizes[0] / 128;  // 20000
  const int ne = in_sizes[1] / 2;    // 160000
  const int H = HID;

  char* p = (char*)d_ws;
  auto alloc = [&](size_t bytes) -> char* {
    char* r = p;
    p += (bytes + 255) & ~(size_t)255;
    return r;
  };
  ushort* hb1   = (ushort*)alloc((size_t)n * H * 2);
  ushort* Sb    = (ushort*)alloc((size_t)n * H * 2);
  ushort* hdb   = (ushort*)alloc((size_t)n * H * 2);
  ushort* xb    = (ushort*)alloc((size_t)n * 128 * 2);
  ushort* w_enc_in  = (ushort*)alloc((size_t)256 * 128 * 2);
  ushort* w_enc_h0  = (ushort*)alloc((size_t)256 * 256 * 2);
  ushort* w_enc_h1  = (ushort*)alloc((size_t)256 * 256 * 2);
  ushort* w_enc_out = (ushort*)alloc((size_t)256 * 256 * 2);
  ushort* w_proc_in  = (ushort*)alloc((size_t)256 * 256 * 2);
  ushort* w_proc_h0  = (ushort*)alloc((size_t)256 * 256 * 2);
  ushort* w_proc_h1  = (ushort*)alloc((size_t)256 * 256 * 2);
  ushort* w_proc_out = (ushort*)alloc((size_t)256 * 256 * 2);
  ushort* w_edge     = (ushort*)alloc((size_t)256 * 512 * 2);
  float* degf   = (float*)alloc((size_t)n * 4);
  float* pooled = (float*)alloc((size_t)NGRAPH * 3 * H * 4);
  float* psum   = (float*)alloc((size_t)256 * H * 4);
  float* pmax   = (float*)alloc((size_t)256 * H * 4);
  float* db0    = (float*)alloc((size_t)NGRAPH * H * 4);
  float* db1    = (float*)alloc((size_t)NGRAPH * H * 4);
  int* cnt    = (int*)alloc((size_t)n * 4);
  int* rowptr = (int*)alloc((size_t)(n + 1) * 4);
  int* cursor = (int*)alloc((size_t)n * 4);
  int* gstart = (int*)alloc((size_t)(NGRAPH + 1) * 4);
  int* gcnt   = (int*)alloc((size_t)NGRAPH * 4);
  int* colv   = (int*)alloc((size_t)ne * 4);

  const int* srcI = ei;
  const int* dstI = ei + ne;

  dim3 blk(256);

  // fused weight conversions (transpose to [N=256][K] bf16)
  WconvArgs wa;
  wa.src[0] = enc_Win;             wa.dst[0] = w_enc_in;   wa.K[0] = 128;
  wa.src[1] = enc_Wh;              wa.dst[1] = w_enc_h0;   wa.K[1] = 256;
  wa.src[2] = enc_Wh + 65536;      wa.dst[2] = w_enc_h1;   wa.K[2] = 256;
  wa.src[3] = enc_Wout;            wa.dst[3] = w_enc_out;  wa.K[3] = 256;
  wa.src[4] = proc_Win;            wa.dst[4] = w_proc_in;  wa.K[4] = 256;
  wa.src[5] = proc_Wh;             wa.dst[5] = w_proc_h0;  wa.K[5] = 256;
  wa.src[6] = proc_Wh + 65536;     wa.dst[6] = w_proc_h1;  wa.K[6] = 256;
  wa.src[7] = proc_Wout;           wa.dst[7] = w_proc_out; wa.K[7] = 256;
  wa.src[8] = edge_W;              wa.dst[8] = w_edge;     wa.K[8] = 512;
  k_wconv_all<<<dim3(16, 8, 9), blk, 0, stream>>>(wa);
  k_f2b<<<dim3((n * 128 / 4 + 255) / 256), blk, 0, stream>>>(x, xb, n * 128);

  // CSR by destination + per-graph bounds
  k_zero_i32<<<dim3((n + 255) / 256), blk, 0, stream>>>(cnt, n);
  k_hist<<<dim3((ne + 255) / 256), blk, 0, stream>>>(dstI, cnt, ne);
  k_scan<<<1, 1024, 0, stream>>>(cnt, rowptr, cursor, n);
  k_gbounds<<<1, 64, 0, stream>>>(batch, n, gstart, gcnt);
  k_scatter<<<dim3((ne + 255) / 256), blk, 0, stream>>>(srcI, dstI, cursor, colv, ne);

  const int npanel = (n + 31) / 32;  // 625 (20000 = 625*32 exactly)

  // fused encoder: 4 layers, one kernel
  MLPArgs ea = {};
  ea.A0 = xb; ea.A1 = nullptr; ea.W0b = nullptr;
  ea.W[0] = w_enc_in; ea.W[1] = w_enc_h0; ea.W[2] = w_enc_h1; ea.W[3] = w_enc_out;
  ea.bias[0] = enc_bin; ea.bias[1] = enc_bh; ea.bias[2] = enc_bh + 256; ea.bias[3] = enc_bout;
  ea.bias[4] = enc_bout;  // unused slot, keep valid pointer
  ea.degf = nullptr; ea.out = hb1; ea.ldw0 = 128;
  ea.actf[0] = 1; ea.actf[1] = 1; ea.actf[2] = 1; ea.actf[3] = 0;
  k_mlp<4, 128, false><<<dim3(npanel), blk, 0, stream>>>(ea, n);

  // fused proc: edge (dual-A) + 4 proc layers, one kernel per MP round
  MLPArgs pa = {};
  pa.A0 = hdb; pa.A1 = Sb; pa.W0b = w_edge + 256;
  pa.W[0] = w_edge; pa.W[1] = w_proc_in; pa.W[2] = w_proc_h0; pa.W[3] = w_proc_h1; pa.W[4] = w_proc_out;
  pa.bias[0] = edge_b; pa.bias[1] = proc_bin; pa.bias[2] = proc_bh; pa.bias[3] = proc_bh + 256; pa.bias[4] = proc_bout;
  pa.degf = degf; pa.out = hb1; pa.ldw0 = 512;
  pa.actf[0] = 0; pa.actf[1] = 1; pa.actf[2] = 1; pa.actf[3] = 1; pa.actf[4] = 0;

  for (int r = 0; r < 4; ++r) {
    k_aggregate<<<dim3((n + 7) / 8), blk, 0, stream>>>(hb1, rowptr, colv, Sb, hdb, degf, n);
    k_mlp<5, 256, true><<<dim3(npanel), blk, 0, stream>>>(pa, n);
  }

  // pooling
  k_pool1<<<dim3(NGRAPH * 16), blk, 0, stream>>>(hb1, gstart, gcnt, psum, pmax);
  k_pool2<<<dim3(NGRAPH), blk, 0, stream>>>(psum, pmax, gcnt, pooled);

  // decoder
  k_dec_layer<<<dim3(4, NGRAPH), blk, 0, stream>>>(pooled, dec_Win, dec_bin, db0, 768, 256, 1);
  k_dec_layer<<<dim3(4, NGRAPH), blk, 0, stream>>>(db0, dec_Wh, dec_bh, db1, 256, 256, 1);
  k_dec_layer<<<dim3(4, NGRAPH), blk, 0, stream>>>(db1, dec_Wh + 65536, dec_bh + 256, db0, 256, 256, 1);
  k_dec_layer<<<dim3(1, NGRAPH), blk, 0, stream>>>(db0, dec_Wout, dec_bout, (float*)d_out, 256, 32, 0);
}